// Round 1
// baseline (3067.018 us; speedup 1.0000x reference)
//
#include <hip/hip_runtime.h>

#define CDIM 128
#define NHEADS 8
#define HD 16
#define NTOK 64
#define HW 65536   // 256*256 pixels per image
#define XS_PAD 132 // float4-aligned (132*4 % 16 == 0)

// ---------------- Kernel 1: fused window QKV + attention ----------------
// grid = 2048 (one block per window), block = 256
__global__ __launch_bounds__(256) void winattn_kernel(
    const float* __restrict__ x, const float* __restrict__ qkv_w,
    const float* __restrict__ qkv_b, const float* __restrict__ rel_bias,
    const int* __restrict__ rel_index, float* __restrict__ attn_out)
{
    __shared__ float xs[NTOK][XS_PAD];   // [token][channel], 33.8 KB
    __shared__ float qh[NTOK][HD];       // 4 KB (reused as oh[d][t] after scores)
    __shared__ float kh[NTOK][17];       // padded: scores read kh[j=lane][d]
    __shared__ float vh[NTOK][HD];       // 4 KB, broadcast reads in PV
    __shared__ float sc[NTOK][65];       // padded: row softmax reads stride 65

    const int tid = threadIdx.x;
    const int wid = blockIdx.x;
    const int b  = wid >> 10;            // window 0..2047 -> batch
    const int wi = wid & 1023;
    const int wy = wi >> 5, wx = wi & 31;
    const int h0 = wy * 8, w0 = wx * 8;
    const float* xb = x + (size_t)b * CDIM * HW;

    // Stage x window: xs[t][c]
    for (int idx = tid; idx < CDIM * NTOK; idx += 256) {
        int c = idx >> 6;
        int t = idx & 63;
        xs[t][c] = xb[c * HW + (h0 + (t >> 3)) * 256 + w0 + (t & 7)];
    }
    __syncthreads();

    float* oh = &qh[0][0];   // overlay: [d][t] layout, 1024 floats

    for (int h = 0; h < NHEADS; ++h) {
        // ---- QKV for this head: 3*64*16 = 3072 dot-128s ----
        for (int idx = tid; idx < 3 * NTOK * HD; idx += 256) {
            int m = idx >> 10;           // 0=q 1=k 2=v (wave-uniform per iter)
            int r = idx & 1023;
            int t = r >> 4;
            int d = r & 15;
            int o = m * CDIM + h * HD + d;
            const float4* wr = (const float4*)(qkv_w + (size_t)o * CDIM);
            const float4* xr = (const float4*)(&xs[t][0]);
            float acc = qkv_b[o];
            #pragma unroll 8
            for (int c4 = 0; c4 < CDIM / 4; ++c4) {
                float4 wv = wr[c4];
                float4 xv = xr[c4];
                acc += wv.x * xv.x + wv.y * xv.y + wv.z * xv.z + wv.w * xv.w;
            }
            if (m == 0)      qh[t][d] = acc;
            else if (m == 1) kh[t][d] = acc;
            else             vh[t][d] = acc;
        }
        __syncthreads();

        // ---- scores: s[i][j] = 0.25 * q_i . k_j + bias ----
        for (int idx = tid; idx < NTOK * NTOK; idx += 256) {
            int i = idx >> 6, j = idx & 63;   // per-wave: i uniform, j = lane
            float acc = 0.f;
            #pragma unroll
            for (int d = 0; d < HD; ++d) acc += qh[i][d] * kh[j][d];
            sc[i][j] = acc * 0.25f + rel_bias[rel_index[i * 64 + j] * NHEADS + h];
        }
        __syncthreads();

        // ---- softmax per row (wave 0, one thread per row) ----
        if (tid < 64) {
            int i = tid;
            float mx = -1e30f;
            for (int j = 0; j < 64; ++j) mx = fmaxf(mx, sc[i][j]);
            float s = 0.f;
            for (int j = 0; j < 64; ++j) { float e = __expf(sc[i][j] - mx); sc[i][j] = e; s += e; }
            float inv = 1.f / s;
            for (int j = 0; j < 64; ++j) sc[i][j] *= inv;
        }
        __syncthreads();

        // ---- PV: out[t][d0..d0+3], thread = (t, d-quad) ----
        {
            int t  = tid >> 2;
            int d0 = (tid & 3) * 4;
            float a0 = 0.f, a1 = 0.f, a2 = 0.f, a3 = 0.f;
            for (int j = 0; j < 64; ++j) {
                float s = sc[t][j];                       // 16-addr broadcast
                const float4 v4 = *(const float4*)&vh[j][d0];  // 4-addr broadcast
                a0 += s * v4.x; a1 += s * v4.y; a2 += s * v4.z; a3 += s * v4.w;
            }
            __syncthreads();            // qh reads (scores) long done; safe to overwrite
            oh[(d0 + 0) * 64 + t] = a0;
            oh[(d0 + 1) * 64 + t] = a1;
            oh[(d0 + 2) * 64 + t] = a2;
            oh[(d0 + 3) * 64 + t] = a3;
        }
        __syncthreads();

        // ---- write head output to global (b, c=h*16+d, h, w) ----
        for (int idx = tid; idx < HD * NTOK; idx += 256) {
            int d = idx >> 6, t = idx & 63;
            attn_out[((size_t)(b * CDIM + h * HD + d)) * HW +
                     (h0 + (t >> 3)) * 256 + w0 + (t & 7)] = oh[d * 64 + t];
        }
        __syncthreads();   // before next head overwrites qh/kh/vh/sc
    }
}

// ---------------- Kernel 2: output projection (pixel GEMM) ----------------
// out[b][o][p] = sum_c proj_w[o][c] * a[b][c][p] + proj_b[o]
// grid = (1024, 2, 2): 64-pixel tile, 64-output half, batch. block = 256.
__global__ __launch_bounds__(256) void proj_kernel(
    const float* __restrict__ a, const float* __restrict__ w,
    const float* __restrict__ bias, float* __restrict__ out)
{
    __shared__ float as[CDIM][64];   // [c][p] 32 KB
    __shared__ float wt[64][68];     // [cc][o] padded, 17 KB

    const int tid = threadIdx.x;
    const int p0 = blockIdx.x * 64;
    const int obase = blockIdx.y * 64;
    const int b = blockIdx.z;
    const float* ab = a + (size_t)b * CDIM * HW;

    for (int idx = tid; idx < CDIM * 64; idx += 256) {
        int c = idx >> 6, p = idx & 63;
        as[c][p] = ab[c * HW + p0 + p];
    }

    const int px = (tid & 15) * 4;   // pixel quad
    const int og = (tid >> 4) * 4;   // output quad
    float acc[4][4] = {};

    for (int c0 = 0; c0 < CDIM; c0 += 64) {
        if (c0) __syncthreads();     // drain compute before overwriting wt
        for (int idx = tid; idx < 64 * 64; idx += 256) {
            int cc = idx & 63, o = idx >> 6;
            wt[cc][o] = w[(size_t)(obase + o) * CDIM + c0 + cc];
        }
        __syncthreads();
        for (int cc = 0; cc < 64; ++cc) {
            const float4 av = *(const float4*)&as[c0 + cc][px];
            const float4 wv = *(const float4*)&wt[cc][og];
            acc[0][0] += wv.x * av.x; acc[0][1] += wv.x * av.y; acc[0][2] += wv.x * av.z; acc[0][3] += wv.x * av.w;
            acc[1][0] += wv.y * av.x; acc[1][1] += wv.y * av.y; acc[1][2] += wv.y * av.z; acc[1][3] += wv.y * av.w;
            acc[2][0] += wv.z * av.x; acc[2][1] += wv.z * av.y; acc[2][2] += wv.z * av.z; acc[2][3] += wv.z * av.w;
            acc[3][0] += wv.w * av.x; acc[3][1] += wv.w * av.y; acc[3][2] += wv.w * av.z; acc[3][3] += wv.w * av.w;
        }
    }

    #pragma unroll
    for (int oo = 0; oo < 4; ++oo) {
        int o = obase + og + oo;
        float bv = bias[o];
        float4 r = make_float4(acc[oo][0] + bv, acc[oo][1] + bv,
                               acc[oo][2] + bv, acc[oo][3] + bv);
        *(float4*)&out[((size_t)b * CDIM + o) * HW + p0 + px] = r;
    }
}

extern "C" void kernel_launch(void* const* d_in, const int* in_sizes, int n_in,
                              void* d_out, int out_size, void* d_ws, size_t ws_size,
                              hipStream_t stream) {
    const float* x        = (const float*)d_in[0];
    const float* qkv_w    = (const float*)d_in[1];
    const float* qkv_b    = (const float*)d_in[2];
    const float* proj_w   = (const float*)d_in[3];
    const float* proj_b   = (const float*)d_in[4];
    const float* rel_bias = (const float*)d_in[5];
    const int*   rel_index= (const int*)d_in[6];
    float* out  = (float*)d_out;
    float* attn = (float*)d_ws;   // 2*128*65536 fp32 = 64 MB

    winattn_kernel<<<2048, 256, 0, stream>>>(x, qkv_w, qkv_b, rel_bias, rel_index, attn);
    proj_kernel<<<dim3(1024, 2, 2), 256, 0, stream>>>(attn, proj_w, proj_b, out);
}

// Round 2
// 254.239 us; speedup vs baseline: 12.0635x; 12.0635x over previous
//
#include <hip/hip_runtime.h>

#define CDIM 128
#define NHEADS 8
#define HD 16
#define NTOK 64
#define HW 65536          // 256*256 pixels per image
#define XSTR 136          // padded row stride (bf16) for 64x128 tiles: 272B -> 2-way-free banks
#define VSTR 72           // padded row stride for [128][64] v^T and [16][64] P tiles

typedef short s8v __attribute__((ext_vector_type(8)));
typedef float f4v __attribute__((ext_vector_type(4)));

static __device__ __forceinline__ short f2bf(float f) {
    unsigned u = __float_as_uint(f);
    u += 0x7FFFu + ((u >> 16) & 1u);   // RNE
    return (short)(u >> 16);
}

static __device__ __forceinline__ s8v pack8(float4 f0, float4 f1) {
    s8v r;
    r[0] = f2bf(f0.x); r[1] = f2bf(f0.y); r[2] = f2bf(f0.z); r[3] = f2bf(f0.w);
    r[4] = f2bf(f1.x); r[5] = f2bf(f1.y); r[6] = f2bf(f1.z); r[7] = f2bf(f1.w);
    return r;
}

// Pre-gather rel_bias[rel_index] -> biasx[h][i*64+j], 8*4096 fp32 = 128 KB (L2-resident)
__global__ __launch_bounds__(256) void bias_kernel(
    const float* __restrict__ rel_bias, const int* __restrict__ rel_index,
    float* __restrict__ biasx)
{
    int idx = blockIdx.x * 256 + threadIdx.x;   // 0..32767
    int h = idx >> 12, ij = idx & 4095;
    biasx[idx] = rel_bias[rel_index[ij] * NHEADS + h];
    (void)h;
}

// One block per 8x8 window. 256 threads = 4 waves.
// Stages: x->LDS bf16 | QKV MFMA GEMM | per-wave attention (2 heads) | fused proj MFMA GEMM.
__global__ __launch_bounds__(256) void winattn_kernel(
    const float* __restrict__ x, const float* __restrict__ qkv_w,
    const float* __restrict__ qkv_b, const float* __restrict__ proj_w,
    const float* __restrict__ proj_b, const float* __restrict__ biasx,
    float* __restrict__ out)
{
    // LDS: 3*17408 + 18432 + 9216 = 79872 B -> 2 blocks/CU
    __shared__ __align__(16) short xs[NTOK * XSTR];     // x window bf16 [t][c]; reused as os (attn out) later
    __shared__ __align__(16) short qs[NTOK * XSTR];     // q [t][c]
    __shared__ __align__(16) short ks[NTOK * XSTR];     // k [t][c]
    __shared__ __align__(16) short vt[CDIM * VSTR];     // v^T [c][t]
    __shared__ __align__(16) short ps[4 * 16 * VSTR];   // per-wave P row-block [16][64]

    const int tid  = threadIdx.x;
    const int lane = tid & 63;
    const int wv   = tid >> 6;        // wave 0..3
    const int qd   = lane >> 4;       // quad 0..3
    const int l15  = lane & 15;

    const int wid = blockIdx.x;
    const int b   = wid >> 10;
    const int wy  = (wid >> 5) & 31, wx = wid & 31;
    const int h0  = wy * 8, w0 = wx * 8;
    const float* xb = x + (size_t)b * CDIM * HW;

    // ---------- Stage 1: stage x window into xs (bf16) ----------
    for (int idx = tid; idx < CDIM * 16; idx += 256) {   // 2048 float4 loads
        int c = idx >> 4, tq = idx & 15;
        int t0 = tq * 4;
        float4 f = *(const float4*)&xb[(size_t)c * HW + (h0 + (t0 >> 3)) * 256 + w0 + (t0 & 7)];
        xs[(t0 + 0) * XSTR + c] = f2bf(f.x);
        xs[(t0 + 1) * XSTR + c] = f2bf(f.y);
        xs[(t0 + 2) * XSTR + c] = f2bf(f.z);
        xs[(t0 + 3) * XSTR + c] = f2bf(f.w);
    }
    __syncthreads();

    // ---------- Stage 2: QKV GEMM: out[t][o] = sum_c xs[t][c]*qkv_w[o][c] + qkv_b[o] ----------
    {
        s8v A[4][4];   // [mt][kc]
        #pragma unroll
        for (int mt = 0; mt < 4; ++mt)
            #pragma unroll
            for (int kc = 0; kc < 4; ++kc)
                A[mt][kc] = *(const s8v*)&xs[(mt * 16 + l15) * XSTR + kc * 32 + qd * 8];

        for (int nt = 0; nt < 6; ++nt) {              // wave covers 96 output channels
            const int o = wv * 96 + nt * 16 + l15;
            const float* wr = qkv_w + (size_t)o * CDIM;
            s8v B[4];
            #pragma unroll
            for (int kc = 0; kc < 4; ++kc) {
                float4 f0 = *(const float4*)&wr[kc * 32 + qd * 8];
                float4 f1 = *(const float4*)&wr[kc * 32 + qd * 8 + 4];
                B[kc] = pack8(f0, f1);
            }
            const float qb = qkv_b[o];
            #pragma unroll
            for (int mt = 0; mt < 4; ++mt) {
                f4v acc = {0.f, 0.f, 0.f, 0.f};
                #pragma unroll
                for (int kc = 0; kc < 4; ++kc)
                    acc = __builtin_amdgcn_mfma_f32_16x16x32_bf16(A[mt][kc], B[kc], acc, 0, 0, 0);
                const int tb = mt * 16 + qd * 4;
                if (o < 128) {
                    #pragma unroll
                    for (int r = 0; r < 4; ++r) qs[(tb + r) * XSTR + o] = f2bf(acc[r] + qb);
                } else if (o < 256) {
                    #pragma unroll
                    for (int r = 0; r < 4; ++r) ks[(tb + r) * XSTR + (o - 128)] = f2bf(acc[r] + qb);
                } else {
                    #pragma unroll
                    for (int r = 0; r < 4; ++r) vt[(o - 256) * VSTR + tb + r] = f2bf(acc[r] + qb);
                }
            }
        }
    }
    __syncthreads();

    // ---------- Stage 3: attention, wave wv handles heads {wv, wv+4} ----------
    // (os overlays xs; xs is dead after stage 2, barrier above protects it)
    short* os = xs;
    const s8v z8 = {};
    #pragma unroll
    for (int pass = 0; pass < 2; ++pass) {
        const int h = wv + pass * 4;
        // hoisted B-frags: k (for S, K padded 16->32 via zeroed quads) and v^T (for PV)
        s8v kf[4];
        #pragma unroll
        for (int nt = 0; nt < 4; ++nt)
            kf[nt] = (qd < 2) ? *(const s8v*)&ks[(nt * 16 + l15) * XSTR + h * HD + qd * 8] : z8;
        s8v vf[2];
        #pragma unroll
        for (int kc = 0; kc < 2; ++kc)
            vf[kc] = *(const s8v*)&vt[(h * HD + l15) * VSTR + kc * 32 + qd * 8];

        #pragma unroll
        for (int mt = 0; mt < 4; ++mt) {
            s8v qf = (qd < 2) ? *(const s8v*)&qs[(mt * 16 + l15) * XSTR + h * HD + qd * 8] : z8;
            float sv[4][4];   // [nt][r]
            #pragma unroll
            for (int nt = 0; nt < 4; ++nt) {
                f4v s = {0.f, 0.f, 0.f, 0.f};
                s = __builtin_amdgcn_mfma_f32_16x16x32_bf16(qf, kf[nt], s, 0, 0, 0);
                const float* bp = biasx + h * 4096 + (mt * 16 + qd * 4) * 64 + nt * 16 + l15;
                #pragma unroll
                for (int r = 0; r < 4; ++r) sv[nt][r] = s[r] * 0.25f + bp[r * 64];
            }
            // softmax rows i = mt*16 + qd*4 + r ; values across {nt} x {16 lanes of quad}
            float inv[4];
            #pragma unroll
            for (int r = 0; r < 4; ++r) {
                float mx = fmaxf(fmaxf(sv[0][r], sv[1][r]), fmaxf(sv[2][r], sv[3][r]));
                #pragma unroll
                for (int off = 1; off < 16; off <<= 1) mx = fmaxf(mx, __shfl_xor(mx, off, 64));
                float sm = 0.f;
                #pragma unroll
                for (int nt = 0; nt < 4; ++nt) { sv[nt][r] = __expf(sv[nt][r] - mx); sm += sv[nt][r]; }
                #pragma unroll
                for (int off = 1; off < 16; off <<= 1) sm += __shfl_xor(sm, off, 64);
                inv[r] = 1.f / sm;
            }
            // write unnormalized P row-block to per-wave LDS
            short* pw = &ps[wv * 16 * VSTR];
            #pragma unroll
            for (int nt = 0; nt < 4; ++nt)
                #pragma unroll
                for (int r = 0; r < 4; ++r)
                    pw[(qd * 4 + r) * VSTR + nt * 16 + l15] = f2bf(sv[nt][r]);
            // PV: O(16x16) = P(16x64) . v(64x16)
            s8v pa0 = *(const s8v*)&pw[l15 * VSTR + 0 * 32 + qd * 8];
            s8v pa1 = *(const s8v*)&pw[l15 * VSTR + 1 * 32 + qd * 8];
            f4v O = {0.f, 0.f, 0.f, 0.f};
            O = __builtin_amdgcn_mfma_f32_16x16x32_bf16(pa0, vf[0], O, 0, 0, 0);
            O = __builtin_amdgcn_mfma_f32_16x16x32_bf16(pa1, vf[1], O, 0, 0, 0);
            #pragma unroll
            for (int r = 0; r < 4; ++r)
                os[(mt * 16 + qd * 4 + r) * XSTR + h * HD + l15] = f2bf(O[r] * inv[r]);
        }
    }
    __syncthreads();

    // ---------- Stage 4: fused proj: out[t][o] = sum_c os[t][c]*proj_w[o][c] + proj_b[o] ----------
    {
        s8v A[4][4];
        #pragma unroll
        for (int mt = 0; mt < 4; ++mt)
            #pragma unroll
            for (int kc = 0; kc < 4; ++kc)
                A[mt][kc] = *(const s8v*)&os[(mt * 16 + l15) * XSTR + kc * 32 + qd * 8];

        s8v B[2][4];
        float pb2[2]; int o2[2];
        #pragma unroll
        for (int nt = 0; nt < 2; ++nt) {
            const int o = wv * 32 + nt * 16 + l15;
            o2[nt] = o;
            pb2[nt] = proj_b[o];
            const float* wr = proj_w + (size_t)o * CDIM;
            #pragma unroll
            for (int kc = 0; kc < 4; ++kc) {
                float4 f0 = *(const float4*)&wr[kc * 32 + qd * 8];
                float4 f1 = *(const float4*)&wr[kc * 32 + qd * 8 + 4];
                B[nt][kc] = pack8(f0, f1);
            }
        }
        #pragma unroll
        for (int mt = 0; mt < 4; ++mt) {
            const int t0 = mt * 16 + qd * 4;
            const int pix = (h0 + (t0 >> 3)) * 256 + w0 + (t0 & 7);
            #pragma unroll
            for (int nt = 0; nt < 2; ++nt) {
                f4v acc = {0.f, 0.f, 0.f, 0.f};
                #pragma unroll
                for (int kc = 0; kc < 4; ++kc)
                    acc = __builtin_amdgcn_mfma_f32_16x16x32_bf16(A[mt][kc], B[nt][kc], acc, 0, 0, 0);
                float4 v = make_float4(acc[0] + pb2[nt], acc[1] + pb2[nt],
                                       acc[2] + pb2[nt], acc[3] + pb2[nt]);
                *(float4*)&out[((size_t)(b * CDIM + o2[nt])) * HW + pix] = v;
            }
        }
    }
}

extern "C" void kernel_launch(void* const* d_in, const int* in_sizes, int n_in,
                              void* d_out, int out_size, void* d_ws, size_t ws_size,
                              hipStream_t stream) {
    const float* x        = (const float*)d_in[0];
    const float* qkv_w    = (const float*)d_in[1];
    const float* qkv_b    = (const float*)d_in[2];
    const float* proj_w   = (const float*)d_in[3];
    const float* proj_b   = (const float*)d_in[4];
    const float* rel_bias = (const float*)d_in[5];
    const int*   rel_index= (const int*)d_in[6];
    float* out   = (float*)d_out;
    float* biasx = (float*)d_ws;   // 8*4096 fp32 = 128 KB

    bias_kernel<<<128, 256, 0, stream>>>(rel_bias, rel_index, biasx);
    winattn_kernel<<<2048, 256, 0, stream>>>(x, qkv_w, qkv_b, proj_w, proj_b, biasx, out);
}

// Round 3
// 203.811 us; speedup vs baseline: 15.0483x; 1.2474x over previous
//
#include <hip/hip_runtime.h>

#define CDIM 128
#define NHEADS 8
#define HD 16
#define NTOK 64
#define HW 65536          // 256*256 pixels per image
#define XSTR 136          // padded row stride (bf16 shorts) for 64x128 tiles
#define VSTR 72           // padded row stride for [128][64] v^T and [16][64] P tiles

typedef short s8v __attribute__((ext_vector_type(8)));
typedef short s4v __attribute__((ext_vector_type(4)));
typedef float f4v __attribute__((ext_vector_type(4)));

static __device__ __forceinline__ short f2bf(float f) {
    unsigned u = __float_as_uint(f);
    u += 0x7FFFu + ((u >> 16) & 1u);   // RNE
    return (short)(u >> 16);
}

// ---- Prologue 1: pack qkv_w (rows 0..383) + proj_w (rows 0..127) into MFMA
// fragment order. frag f = ob*4+kc; ob 0..7 = q (pre-scaled 0.25), 8..15 = k,
// 16..23 = v, 24..31 = proj.  wpk[(f*64+lane)*8 + j] =
//   W[ob*16 + (lane&15)][kc*32 + (lane>>4)*8 + j]
__global__ __launch_bounds__(256) void pack_w_kernel(
    const float* __restrict__ qkv_w, const float* __restrict__ proj_w,
    short* __restrict__ wpk)
{
    int idx = blockIdx.x * 256 + threadIdx.x;   // 0..8191
    int lane = idx & 63, kc = (idx >> 6) & 3, ob = idx >> 8;
    int row = (ob < 24) ? ob * 16 + (lane & 15) : (ob - 24) * 16 + (lane & 15);
    int col = kc * 32 + (lane >> 4) * 8;
    const float* src = ((ob < 24) ? qkv_w : proj_w) + (size_t)row * CDIM + col;
    float sc = (ob < 8) ? 0.25f : 1.0f;
    float4 f0 = *(const float4*)src;
    float4 f1 = *(const float4*)(src + 4);
    s8v r;
    r[0] = f2bf(f0.x * sc); r[1] = f2bf(f0.y * sc);
    r[2] = f2bf(f0.z * sc); r[3] = f2bf(f0.w * sc);
    r[4] = f2bf(f1.x * sc); r[5] = f2bf(f1.y * sc);
    r[6] = f2bf(f1.z * sc); r[7] = f2bf(f1.w * sc);
    *(s8v*)&wpk[(size_t)idx * 8] = r;
}

// ---- Prologue 2: gather rel_bias[rel_index] into C-fragment order:
// biasf[(((h*4+mt)*4+nt)*64 + lane)*4 + r] = bias[h][i=mt*16+(lane>>4)*4+r][j=nt*16+(lane&15)]
__global__ __launch_bounds__(256) void pack_b_kernel(
    const float* __restrict__ rel_bias, const int* __restrict__ rel_index,
    float* __restrict__ biasf)
{
    int idx = blockIdx.x * 256 + threadIdx.x;   // 0..8191
    int lane = idx & 63, nt = (idx >> 6) & 3, mt = (idx >> 8) & 3, h = idx >> 10;
    int j  = nt * 16 + (lane & 15);
    int i0 = mt * 16 + (lane >> 4) * 4;
    f4v v;
    #pragma unroll
    for (int r = 0; r < 4; ++r)
        v[r] = rel_bias[rel_index[(i0 + r) * 64 + j] * NHEADS + h];
    *(f4v*)&biasf[(size_t)idx * 4] = v;
}

// ---- Main: one block per 8x8 window, 256 threads = 4 waves ----
__global__ __launch_bounds__(256) void winattn_kernel(
    const float* __restrict__ x, const float* __restrict__ qkv_b,
    const float* __restrict__ proj_b, const short* __restrict__ wpk,
    const float* __restrict__ biasf, float* __restrict__ out)
{
    __shared__ __align__(16) short xs[NTOK * XSTR];     // x [t][c]; reused as os later
    __shared__ __align__(16) short qs[NTOK * XSTR];     // q [t][c] (pre-scaled 0.25)
    __shared__ __align__(16) short ks[NTOK * XSTR];     // k [t][c]
    __shared__ __align__(16) short vt[CDIM * VSTR];     // v^T [c][t]
    __shared__ __align__(16) short ps[4 * 16 * VSTR];   // per-wave P row-block [16][64]

    const int tid  = threadIdx.x;
    const int lane = tid & 63;
    const int wv   = tid >> 6;
    const int qd   = lane >> 4;
    const int l15  = lane & 15;

    // XCD swizzle: consecutive logical windows -> same XCD (L2 line sharing for x)
    const int wid = (blockIdx.x & 7) * 256 + (blockIdx.x >> 3);
    const int b   = wid >> 10;
    const int wy  = (wid >> 5) & 31, wx = wid & 31;
    const int h0  = wy * 8, w0 = wx * 8;
    const float* xb = x + (size_t)b * CDIM * HW;

    // ---------- Stage 1: stage x window into xs (bf16) ----------
    for (int idx = tid; idx < CDIM * 16; idx += 256) {
        int c = idx >> 4, tq = idx & 15;
        int t0 = tq * 4;
        float4 f = *(const float4*)&xb[(size_t)c * HW + (h0 + (t0 >> 3)) * 256 + w0 + (t0 & 7)];
        xs[(t0 + 0) * XSTR + c] = f2bf(f.x);
        xs[(t0 + 1) * XSTR + c] = f2bf(f.y);
        xs[(t0 + 2) * XSTR + c] = f2bf(f.z);
        xs[(t0 + 3) * XSTR + c] = f2bf(f.w);
    }
    __syncthreads();

    // ---------- Stage 2: QKV GEMM from prepacked fragments ----------
    {
        s8v X[4][4];   // [tb][kc] — serves as A-frag (m=t) or B-frag (n=t)
        #pragma unroll
        for (int tb = 0; tb < 4; ++tb)
            #pragma unroll
            for (int kc = 0; kc < 4; ++kc)
                X[tb][kc] = *(const s8v*)&xs[(tb * 16 + l15) * XSTR + kc * 32 + qd * 8];

        const s8v* wf = (const s8v*)wpk;
        #pragma unroll
        for (int i = 0; i < 6; ++i) {
            const int ob = wv * 6 + i;    // 0..23, wave-uniform
            s8v W[4];
            #pragma unroll
            for (int kc = 0; kc < 4; ++kc) W[kc] = wf[(ob * 4 + kc) * 64 + lane];
            if (ob < 16) {
                // q/k: D[m=o][n=t]; lane: col=t(l15), rows=o0..o0+3
                const int o0 = ob * 16 + qd * 4;
                float4 qb4 = *(const float4*)&qkv_b[o0];
                const float bsc = (ob < 8) ? 0.25f : 1.0f;
                float qb[4] = {qb4.x * bsc, qb4.y * bsc, qb4.z * bsc, qb4.w * bsc};
                #pragma unroll
                for (int tb = 0; tb < 4; ++tb) {
                    f4v acc = {0.f, 0.f, 0.f, 0.f};
                    #pragma unroll
                    for (int kc = 0; kc < 4; ++kc)
                        acc = __builtin_amdgcn_mfma_f32_16x16x32_bf16(W[kc], X[tb][kc], acc, 0, 0, 0);
                    const int t = tb * 16 + l15;
                    s4v pk;
                    #pragma unroll
                    for (int r = 0; r < 4; ++r) pk[r] = f2bf(acc[r] + qb[r]);
                    if (o0 < 128) *(s4v*)&qs[t * XSTR + o0]       = pk;
                    else          *(s4v*)&ks[t * XSTR + o0 - 128] = pk;
                }
            } else {
                // v: D[m=t][n=o]; lane: col=o(l15), rows=t0..t0+3 -> v^T writes
                const int o = (ob - 16) * 16 + l15;
                const float vb = qkv_b[256 + o];
                #pragma unroll
                for (int tb = 0; tb < 4; ++tb) {
                    f4v acc = {0.f, 0.f, 0.f, 0.f};
                    #pragma unroll
                    for (int kc = 0; kc < 4; ++kc)
                        acc = __builtin_amdgcn_mfma_f32_16x16x32_bf16(X[tb][kc], W[kc], acc, 0, 0, 0);
                    const int t0 = tb * 16 + qd * 4;
                    s4v pk;
                    #pragma unroll
                    for (int r = 0; r < 4; ++r) pk[r] = f2bf(acc[r] + vb);
                    *(s4v*)&vt[o * VSTR + t0] = pk;
                }
            }
        }
    }
    __syncthreads();

    // ---------- Stage 3: attention, wave wv handles heads {wv, wv+4} ----------
    short* os = xs;   // overlay (xs dead after stage 2; barrier above)
    const s8v z8 = {};
    #pragma unroll
    for (int pass = 0; pass < 2; ++pass) {
        const int h = wv + pass * 4;
        s8v kf[4];
        #pragma unroll
        for (int nt = 0; nt < 4; ++nt)
            kf[nt] = (qd < 2) ? *(const s8v*)&ks[(nt * 16 + l15) * XSTR + h * HD + qd * 8] : z8;
        s8v vf[2];
        #pragma unroll
        for (int kc = 0; kc < 2; ++kc)
            vf[kc] = *(const s8v*)&vt[(h * HD + l15) * VSTR + kc * 32 + qd * 8];

        #pragma unroll
        for (int mt = 0; mt < 4; ++mt) {
            s8v qf = (qd < 2) ? *(const s8v*)&qs[(mt * 16 + l15) * XSTR + h * HD + qd * 8] : z8;
            float sv[4][4];
            #pragma unroll
            for (int nt = 0; nt < 4; ++nt) {
                f4v s = {0.f, 0.f, 0.f, 0.f};
                s = __builtin_amdgcn_mfma_f32_16x16x32_bf16(qf, kf[nt], s, 0, 0, 0);
                f4v bf = *(const f4v*)&biasf[(size_t)(((h * 4 + mt) * 4 + nt) * 64 + lane) * 4];
                #pragma unroll
                for (int r = 0; r < 4; ++r) sv[nt][r] = s[r] + bf[r];   // scale folded into q
            }
            float inv[4];
            #pragma unroll
            for (int r = 0; r < 4; ++r) {
                float mx = fmaxf(fmaxf(sv[0][r], sv[1][r]), fmaxf(sv[2][r], sv[3][r]));
                #pragma unroll
                for (int off = 1; off < 16; off <<= 1) mx = fmaxf(mx, __shfl_xor(mx, off, 64));
                float sm = 0.f;
                #pragma unroll
                for (int nt = 0; nt < 4; ++nt) { sv[nt][r] = __expf(sv[nt][r] - mx); sm += sv[nt][r]; }
                #pragma unroll
                for (int off = 1; off < 16; off <<= 1) sm += __shfl_xor(sm, off, 64);
                inv[r] = 1.f / sm;
            }
            short* pw = &ps[wv * 16 * VSTR];
            #pragma unroll
            for (int nt = 0; nt < 4; ++nt) {
                s4v pk;
                #pragma unroll
                for (int r = 0; r < 4; ++r) pk[r] = f2bf(sv[nt][r]);
                // rows qd*4+r, cols nt*16+l15 -> column writes (scalar shorts)
                pw[(qd * 4 + 0) * VSTR + nt * 16 + l15] = pk[0];
                pw[(qd * 4 + 1) * VSTR + nt * 16 + l15] = pk[1];
                pw[(qd * 4 + 2) * VSTR + nt * 16 + l15] = pk[2];
                pw[(qd * 4 + 3) * VSTR + nt * 16 + l15] = pk[3];
            }
            s8v pa0 = *(const s8v*)&pw[l15 * VSTR + 0 * 32 + qd * 8];
            s8v pa1 = *(const s8v*)&pw[l15 * VSTR + 1 * 32 + qd * 8];
            f4v O = {0.f, 0.f, 0.f, 0.f};
            O = __builtin_amdgcn_mfma_f32_16x16x32_bf16(pa0, vf[0], O, 0, 0, 0);
            O = __builtin_amdgcn_mfma_f32_16x16x32_bf16(pa1, vf[1], O, 0, 0, 0);
            #pragma unroll
            for (int r = 0; r < 4; ++r)
                os[(mt * 16 + qd * 4 + r) * XSTR + h * HD + l15] = f2bf(O[r] * inv[r]);
        }
    }
    __syncthreads();

    // ---------- Stage 4: fused proj from prepacked fragments ----------
    {
        s8v A[4][4];
        #pragma unroll
        for (int mt = 0; mt < 4; ++mt)
            #pragma unroll
            for (int kc = 0; kc < 4; ++kc)
                A[mt][kc] = *(const s8v*)&os[(mt * 16 + l15) * XSTR + kc * 32 + qd * 8];

        const s8v* wf = (const s8v*)wpk;
        s8v B[2][4];
        float pb2[2]; int o2[2];
        #pragma unroll
        for (int nt = 0; nt < 2; ++nt) {
            const int ob = 24 + wv * 2 + nt;
            o2[nt] = (wv * 2 + nt) * 16 + l15;
            pb2[nt] = proj_b[o2[nt]];
            #pragma unroll
            for (int kc = 0; kc < 4; ++kc) B[nt][kc] = wf[(ob * 4 + kc) * 64 + lane];
        }
        #pragma unroll
        for (int mt = 0; mt < 4; ++mt) {
            const int t0 = mt * 16 + qd * 4;
            const int pix = (h0 + (t0 >> 3)) * 256 + w0 + (t0 & 7);
            #pragma unroll
            for (int nt = 0; nt < 2; ++nt) {
                f4v acc = {0.f, 0.f, 0.f, 0.f};
                #pragma unroll
                for (int kc = 0; kc < 4; ++kc)
                    acc = __builtin_amdgcn_mfma_f32_16x16x32_bf16(A[mt][kc], B[nt][kc], acc, 0, 0, 0);
                float4 v = make_float4(acc[0] + pb2[nt], acc[1] + pb2[nt],
                                       acc[2] + pb2[nt], acc[3] + pb2[nt]);
                *(float4*)&out[((size_t)(b * CDIM + o2[nt])) * HW + pix] = v;
            }
        }
    }
}

extern "C" void kernel_launch(void* const* d_in, const int* in_sizes, int n_in,
                              void* d_out, int out_size, void* d_ws, size_t ws_size,
                              hipStream_t stream) {
    const float* x        = (const float*)d_in[0];
    const float* qkv_w    = (const float*)d_in[1];
    const float* qkv_b    = (const float*)d_in[2];
    const float* proj_w   = (const float*)d_in[3];
    const float* proj_b   = (const float*)d_in[4];
    const float* rel_bias = (const float*)d_in[5];
    const int*   rel_index= (const int*)d_in[6];
    float* out = (float*)d_out;

    short* wpk   = (short*)d_ws;                       // 32*4*64*8 shorts = 128 KB
    float* biasf = (float*)((char*)d_ws + 131072);     // 8192 float4 = 128 KB

    pack_w_kernel<<<32, 256, 0, stream>>>(qkv_w, proj_w, wpk);
    pack_b_kernel<<<32, 256, 0, stream>>>(rel_bias, rel_index, biasf);
    winattn_kernel<<<2048, 256, 0, stream>>>(x, qkv_b, proj_b, wpk, biasf, out);
}